// Round 16
// baseline (26.455 us; speedup 1.0000x reference)
//
#include <hip/hip_runtime.h>
#include <cmath>

// Problem constants: B=4, L=8192, H=128, P=64
constexpr int Bn = 4;
constexpr int Ln = 8192;
constexpr int Hn = 128;
constexpr int Pn = 64;
constexpr int Kn = 128;         // 2*P interleaved (k = 2p+c)
constexpr int Sc = 64;          // chunk length (rows per block)
constexpr int NC = Ln / Sc;     // 128 chunks per batch
constexpr int NBLK = Bn * NC;   // 512 blocks

typedef float f4 __attribute__((ext_vector_type(4)));
typedef float f32x4 __attribute__((ext_vector_type(4)));
typedef unsigned short us8 __attribute__((ext_vector_type(8)));
typedef unsigned short us4 __attribute__((ext_vector_type(4)));
typedef __bf16 bf16x8 __attribute__((ext_vector_type(8)));

__device__ __forceinline__ unsigned short f2bf(float f) {
  unsigned u = __builtin_bit_cast(unsigned, f);
  u += 0x7fffu + ((u >> 16) & 1u);        // round-to-nearest-even
  return (unsigned short)(u >> 16);
}
__device__ __forceinline__ float bf2f(unsigned short v) {
  return __builtin_bit_cast(float, (unsigned)v << 16);
}

__device__ __forceinline__ f32x4 mfma_bf16(us8 a, us8 b, f32x4 c) {
  return __builtin_amdgcn_mfma_f32_16x16x32_bf16(
      __builtin_bit_cast(bf16x8, a), __builtin_bit_cast(bf16x8, b), c, 0, 0, 0);
}

__device__ __forceinline__ void make_M(float A, float st,
    float& m11, float& m12, float& m21, float& m22) {
  float s2A   = st * st * A;
  float schur = 1.0f / (1.0f + s2A);
  m11 = 1.0f - s2A * schur;
  m12 = -st * A * schur;
  m21 = st * schur;
  m22 = schur;
}

struct M22 { float a, b, c, d; };   // [[a,b],[c,d]]
__device__ __forceinline__ M22 mmul(M22 X, M22 Y) {
  return { X.a * Y.a + X.b * Y.c, X.a * Y.b + X.b * Y.d,
           X.c * Y.a + X.d * Y.c, X.c * Y.b + X.d * Y.d };
}

// W-in-LDS swizzle: row n (256B), byte ^= (n&7)<<4  (read & write use same involution)
__device__ __forceinline__ char* wswz(unsigned short* wlds, int n, int byteInRow) {
  return (char*)wlds + ((n * 256 + byteInRow) ^ ((n & 7) << 4));
}
__device__ __forceinline__ const char* wswz_c(const unsigned short* wlds, int n, int byteInRow) {
  return (const char*)wlds + ((n * 256 + byteInRow) ^ ((n & 7) << 4));
}

// stage u tile -> bf16 swizzled LDS (r13-proven)
__device__ __forceinline__ void stage_u(const f4* __restrict__ u4,
                                        unsigned short* usb, int t) {
  #pragma unroll
  for (int i = 0; i < 8; ++i) {
    int idx = t + i * 256;
    f4 v = u4[idx];
    int row = idx >> 5, c0 = (idx & 31) * 4;
    us4 pk = {f2bf(v[0]), f2bf(v[1]), f2bf(v[2]), f2bf(v[3])};
    *(us4*)((char*)usb + ((row * 256 + c0 * 2) ^ ((row & 7) << 4))) = pk;
  }
}

// stage Wb -> LDS bf16 (swizzled): WbN[n][h] = (n&1?Bi:Br)[n>>1][h]  (r13-proven)
__device__ __forceinline__ void stage_wb(const float* __restrict__ Br,
                                         const float* __restrict__ Bi,
                                         unsigned short* wlds, int t) {
  #pragma unroll
  for (int i = 0; i < 16; ++i) {
    int idx4 = t + i * 256;                 // 0..4095 us4-groups
    int n = idx4 >> 5, h4 = idx4 & 31;      // h = 4*h4
    const float* __restrict__ src = ((n & 1) ? Bi : Br) + (n >> 1) * Hn + h4 * 4;
    f4 w = *(const f4*)src;
    us4 pk = {f2bf(w[0]), f2bf(w[1]), f2bf(w[2]), f2bf(w[3])};
    *(us4*)wswz(wlds, n, h4 * 8) = pk;
  }
}

// GEMM tile: A-frags from usb (swz), B-frags from wlds (swz), accs in regs, then spill to outlds
__device__ __forceinline__ void gemm_regs(const unsigned short* __restrict__ usb,
                                          const unsigned short* __restrict__ wlds,
                                          f32x4* accs, int t) {
  const int wave = t >> 6, lane = t & 63;
  const int arow = wave * 16 + (lane & 15);
  const int kg = lane >> 4;                 // k = kk*32 + kg*8 + j

  us8 afr[4];
  #pragma unroll
  for (int kk = 0; kk < 4; ++kk)
    afr[kk] = *(const us8*)((const char*)usb +
        ((arow * 256 + kk * 64 + kg * 16) ^ ((arow & 7) << 4)));

  #pragma unroll
  for (int nt = 0; nt < 8; ++nt) {
    const int n = nt * 16 + (lane & 15);
    f32x4 acc = {0.f, 0.f, 0.f, 0.f};
    #pragma unroll
    for (int kk = 0; kk < 4; ++kk) {
      us8 bfr = *(const us8*)wswz_c(wlds, n, kk * 64 + kg * 16);
      acc = mfma_bf16(afr[kk], bfr, acc);
    }
    accs[nt] = acc;
  }
}

__device__ __forceinline__ void spill_accs(const f32x4* accs, float* outlds, int t) {
  const int wave = t >> 6, lane = t & 63;
  const int crow = wave * 16 + (lane >> 4) * 4;   // verified m89 C/D mapping
  #pragma unroll
  for (int nt = 0; nt < 8; ++nt) {
    const int ccol = nt * 16 + (lane & 15);
    #pragma unroll
    for (int r = 0; r < 4; ++r)
      outlds[(crow + r) * Kn + ccol] = accs[nt][r];
  }
}

// ------------------------------------------------- K1: Wb->LDS + GEMM1(reg) + zero-init scan -> carry only
__global__ __launch_bounds__(256) void k1_kernel(
    const float* __restrict__ u, const float* __restrict__ Br,
    const float* __restrict__ Bi, const float* __restrict__ Ad,
    const float* __restrict__ steps, float2* __restrict__ carry) {
  __shared__ unsigned short usb[Sc * Hn];   // 16 KB: u-tile (swz)
  __shared__ float bu[Sc * Kn];             // 32 KB: first Wb bf16 (swz), then Bu f32
  unsigned short* wlds = (unsigned short*)bu;
  const int t = threadIdx.x;
  const int b = blockIdx.x >> 7;            // NC = 128
  const int chunk = blockIdx.x & (NC - 1);
  const size_t row0 = (size_t)b * Ln + (size_t)chunk * Sc;

  stage_u((const f4*)(u + row0 * Hn), usb, t);
  stage_wb(Br, Bi, wlds, t);
  __syncthreads();

  f32x4 accs[8];
  gemm_regs(usb, wlds, accs, t);
  __syncthreads();          // all W reads complete before clobbering with Bu
  spill_accs(accs, bu, t);
  __syncthreads();

  // local zero-init scan; carry -> global (no ys output)
  if (t < Kn) {
    const int p = t >> 1;
    const float A  = fmaxf(Ad[p], 0.0f);
    const float st = 1.0f / (1.0f + expf(-steps[p]));
    float m11, m12, m21, m22;
    make_M(A, st, m11, m12, m21, m22);
    const float f1 = m11 * st, f2 = m21 * st;
    float z = 0.f, x = 0.f;
    #pragma unroll 8
    for (int s = 0; s < Sc; ++s) {
      float bv = bu[s * Kn + t];
      float zn = fmaf(m11, z, fmaf(m12, x, f1 * bv));
      float xn = fmaf(m21, z, fmaf(m22, x, f2 * bv));
      z = zn; x = xn;
    }
    carry[((size_t)b * NC + chunk) * Kn + t] = make_float2(z, x);
  }
}

// ------------------------------------------------- K2: wave-parallel carry propagation (proven r8)
__global__ __launch_bounds__(256) void k2_propagate(
    const float* __restrict__ Ad, const float* __restrict__ steps,
    float2* __restrict__ carry) {
  const int wave = threadIdx.x >> 6, lane = threadIdx.x & 63;
  const int series = blockIdx.x * 4 + wave;   // 0..511
  const int sb = series >> 7;
  const int k = series & 127;
  const int p = k >> 1;

  const float A  = fmaxf(Ad[p], 0.0f);
  const float st = 1.0f / (1.0f + expf(-steps[p]));
  float m11, m12, m21, m22;
  make_M(A, st, m11, m12, m21, m22);
  // Mc = M^Sc (Sc=64 -> 6 squarings)
  float ca = m11, cb = m12, cc = m21, cd = m22;
  #pragma unroll
  for (int i = 0; i < 6; ++i) {
    float na = ca * ca + cb * cc;
    float nb = ca * cb + cb * cd;
    float nc = cc * ca + cd * cc;
    float nd = cc * cb + cd * cd;
    ca = na; cb = nb; cc = nc; cd = nd;
  }

  const size_t base = (size_t)sb * NC * Kn + k;
  float2 c0 = carry[base + (size_t)(2 * lane) * Kn];
  float2 c1 = carry[base + (size_t)(2 * lane + 1) * Kn];

  // lane-local fold of chunks {2i, 2i+1}
  float Aa = ca * ca + cb * cc;
  float Ab = ca * cb + cb * cd;
  float Ac = cc * ca + cd * cc;
  float Adl = cc * cb + cd * cd;
  float bz = ca * c0.x + cb * c0.y + c1.x;
  float bx = cc * c0.x + cd * c0.y + c1.y;

  // inclusive shfl-scan of affine maps
  #pragma unroll
  for (int d = 1; d < 64; d <<= 1) {
    float oAa = __shfl_up(Aa, d), oAb = __shfl_up(Ab, d);
    float oAc = __shfl_up(Ac, d), oAd = __shfl_up(Adl, d);
    float obz = __shfl_up(bz, d), obx = __shfl_up(bx, d);
    if (lane >= d) {
      float nbz = Aa * obz + Ab * obx + bz;
      float nbx = Ac * obz + Adl * obx + bx;
      float nAa = Aa * oAa + Ab * oAc;
      float nAb = Aa * oAb + Ab * oAd;
      float nAc = Ac * oAa + Adl * oAc;
      float nAd = Ac * oAb + Adl * oAd;
      Aa = nAa; Ab = nAb; Ac = nAc; Adl = nAd; bz = nbz; bx = nbx;
    }
  }

  // exclusive prefix; init for chunk 2i, then 2i+1 = Mc*init + c0
  float ebz = __shfl_up(bz, 1);
  float ebx = __shfl_up(bx, 1);
  if (lane == 0) { ebz = 0.f; ebx = 0.f; }

  carry[base + (size_t)(2 * lane) * Kn]     = make_float2(ebz, ebx);
  carry[base + (size_t)(2 * lane + 1) * Kn] =
      make_float2(ca * ebz + cb * ebx + c0.x, cc * ebz + cd * ebx + c0.y);
}

// ------------------------------------------------- K3: Wb->LDS + GEMM1 + init-rescan + Wc->LDS + GEMM2 + residual
__global__ __launch_bounds__(256) void k3_kernel(
    const float* __restrict__ u, const float* __restrict__ Br,
    const float* __restrict__ Bi, const float* __restrict__ Cr,
    const float* __restrict__ Ci, const float* __restrict__ Dv,
    const float* __restrict__ Ad, const float* __restrict__ steps,
    const float2* __restrict__ carry, float* __restrict__ out) {
  __shared__ unsigned short usb[Sc * Hn];   // 16 KB: u bf16 (swz), later ys bf16 (swz)
  __shared__ float bu[Sc * Kn];             // 32 KB: Wb -> Bu f32 -> ys f32 -> Wc -> olds f32
  unsigned short* wlds = (unsigned short*)bu;
  const int t = threadIdx.x;
  const int b = blockIdx.x >> 7;
  const int chunk = blockIdx.x & (NC - 1);
  const size_t row0 = (size_t)b * Ln + (size_t)chunk * Sc;
  const f4* __restrict__ u4 = (const f4*)(u + row0 * Hn);

  stage_u(u4, usb, t);
  stage_wb(Br, Bi, wlds, t);
  __syncthreads();

  // GEMM1 (recompute Bu; cheap now that W is LDS-staged)
  f32x4 accs[8];
  gemm_regs(usb, wlds, accs, t);
  __syncthreads();
  spill_accs(accs, bu, t);
  __syncthreads();

  // initialized rescan: overwrite bu with ys (x component) — full f32, no correction needed
  if (t < Kn) {
    const int p = t >> 1;
    const float A  = fmaxf(Ad[p], 0.0f);
    const float st = 1.0f / (1.0f + expf(-steps[p]));
    float m11, m12, m21, m22;
    make_M(A, st, m11, m12, m21, m22);
    const float f1 = m11 * st, f2 = m21 * st;
    float2 init = carry[((size_t)b * NC + chunk) * Kn + t];
    float z = init.x, x = init.y;
    #pragma unroll 8
    for (int s = 0; s < Sc; ++s) {
      float bv = bu[s * Kn + t];
      float zn = fmaf(m11, z, fmaf(m12, x, f1 * bv));
      float xn = fmaf(m21, z, fmaf(m22, x, f2 * bv));
      z = zn; x = xn;
      bu[s * Kn + t] = x;
    }
  }
  __syncthreads();

  // pack ys f32 -> usb bf16 swizzled (clobbers u tile; epilogue re-reads u from L2)
  #pragma unroll
  for (int i = 0; i < 8; ++i) {
    int idx = t + i * 256;
    int row = idx >> 5, c0 = (idx & 31) * 4;
    f4 v = *(const f4*)&bu[row * Kn + c0];
    us4 pk = {f2bf(v[0]), f2bf(v[1]), f2bf(v[2]), f2bf(v[3])};
    *(us4*)((char*)usb + ((row * 256 + c0 * 2) ^ ((row & 7) << 4))) = pk;
  }
  __syncthreads();

  // stage Wc -> wlds (clobbers ys f32; already packed): WcH[h][k] = (k&1 ? -Ci : Cr)[h][k>>1]
  #pragma unroll
  for (int i = 0; i < 16; ++i) {
    int idx4 = t + i * 256;
    int h = idx4 >> 5, k4 = (idx4 & 31) * 4;
    const float2 cr = *(const float2*)(Cr + h * Pn + (k4 >> 1));
    const float2 ci = *(const float2*)(Ci + h * Pn + (k4 >> 1));
    us4 pk = {f2bf(cr.x), f2bf(-ci.x), f2bf(cr.y), f2bf(-ci.y)};
    *(us4*)wswz(wlds, h, k4 * 2) = pk;
  }
  __syncthreads();

  // GEMM2
  gemm_regs(usb, wlds, accs, t);
  __syncthreads();
  spill_accs(accs, bu, t);
  __syncthreads();

  // residual + coalesced store (r13-proven epilogue; u re-read is L2-hot)
  const f4* __restrict__ Dv4 = (const f4*)Dv;
  f4* __restrict__ out4 = (f4*)out;
  #pragma unroll
  for (int i = 0; i < 8; ++i) {
    int idx = t + i * 256;
    int row = idx >> 5, c0 = (idx & 31) * 4;
    f4 acc = *(const f4*)&bu[row * Kn + c0];
    f4 uv = u4[idx];
    f4 dv = Dv4[idx & 31];
    f4 res;
    #pragma unroll
    for (int j = 0; j < 4; ++j) res[j] = fmaf(uv[j], dv[j], acc[j]);
    out4[row0 * (Hn / 4) + idx] = res;
  }
}

extern "C" void kernel_launch(void* const* d_in, const int* in_sizes, int n_in,
                              void* d_out, int out_size, void* d_ws, size_t ws_size,
                              hipStream_t stream) {
  const float* u     = (const float*)d_in[0];
  const float* Ad    = (const float*)d_in[1];
  const float* Br    = (const float*)d_in[2];
  const float* Bi    = (const float*)d_in[3];
  const float* Cr    = (const float*)d_in[4];
  const float* Ci    = (const float*)d_in[5];
  const float* Dv    = (const float*)d_in[6];
  const float* steps = (const float*)d_in[7];
  float* out = (float*)d_out;

  // ws: carry [B*NC*Kn float2 = 512KB]
  float2* carry = (float2*)d_ws;

  k1_kernel   <<<NBLK,        256, 0, stream>>>(u, Br, Bi, Ad, steps, carry);
  k2_propagate<<<Bn * Kn / 4, 256, 0, stream>>>(Ad, steps, carry);
  k3_kernel   <<<NBLK,        256, 0, stream>>>(u, Br, Bi, Cr, Ci, Dv, Ad, steps, carry, out);
}